// Round 13
// baseline (89.422 us; speedup 1.0000x reference)
//
#include <hip/hip_runtime.h>
#include <math.h>

#define N_Q     16384
#define DDIM    512
#define M_SLOTS 2048
#define EPSN    1e-12f
#define TEMPU   1e-5f
#define KSCALE  25.4f                    // int8 scale for keys (clips at ~5 sigma)
#define QSCALE  127.0f
#define INV_S   (1.0f / (127.0f * 25.4f))
#define NZBLK   73                       // zero-fill blocks appended to k_prep (73*2048B)
#define BCAP    32                       // bucket capacity per slot (Poisson(8): P(>32)~1e-9)
#define PBLK    768                      // persistent k_score blocks (3 per CU)

typedef unsigned int u32;
typedef unsigned long long u64;
typedef __attribute__((ext_vector_type(4))) int i32x4;

// ---------- helpers ----------
__device__ __forceinline__ void gld_lds16(const void* g, void* l) {
    __builtin_amdgcn_global_load_lds(
        (const __attribute__((address_space(1))) u32*)(g),
        (__attribute__((address_space(3))) u32*)(l), 16, 0, 0);
}
__device__ __forceinline__ float block_reduce_sum_128(float v, float* sred, int t) {
    #pragma unroll
    for (int o = 32; o > 0; o >>= 1) v += __shfl_down(v, o, 64);
    if ((t & 63) == 0) sred[t >> 6] = v;
    __syncthreads();
    return sred[0] + sred[1];
}
__device__ __forceinline__ char q8(float x, float s) {
    int v = __float2int_rn(x * s);
    v = v < -127 ? -127 : (v > 127 ? 127 : v);
    return (char)v;
}

// ---------- kernel 1: normalize+quantize queries / keys->i8 / zero-fill scratch ----------
__global__ __launch_bounds__(128) void k_prep(const float* __restrict__ q,
                                              const float* __restrict__ keys,
                                              char* __restrict__ qi8,
                                              char* __restrict__ ki8,
                                              float4* __restrict__ zbase) {
    __shared__ float sred[2];
    int b = blockIdx.x;
    int t = threadIdx.x;
    if (b < N_Q) {
        float4 v = ((const float4*)(q + (size_t)b * DDIM))[t];
        float ss = v.x * v.x + v.y * v.y + v.z * v.z + v.w * v.w;
        ss = block_reduce_sum_128(ss, sred, t);
        float s = QSCALE / fmaxf(sqrtf(ss), EPSN);
        char4 o;
        o.x = q8(v.x, s);
        o.y = q8(v.y, s);
        o.z = q8(v.z, s);
        o.w = q8(v.w, s);
        ((char4*)(qi8 + (size_t)b * DDIM))[t] = o;
    } else if (b < N_Q + M_SLOTS) {
        int r = b - N_Q;
        float4 v = ((const float4*)(keys + (size_t)r * DDIM))[t];
        char4 o;
        o.x = q8(v.x, KSCALE);
        o.y = q8(v.y, KSCALE);
        o.z = q8(v.z, KSCALE);
        o.w = q8(v.w, KSCALE);
        ((char4*)(ki8 + (size_t)r * DDIM))[t] = o;
    } else {
        // zero rowpack(131072) + colmax(8192) + cur(8192) + ovf_cnt pad(2048)
        int idx = (b - (N_Q + M_SLOTS)) * 128 + t;
        zbase[idx] = make_float4(0.f, 0.f, 0.f, 0.f);
    }
}

// ---------- kernel 2: persistent i8 MFMA score GEMM ----------
// 768 blocks (3/CU), each handles 2-3 128x128 tiles. The r7-proven 3-buffer
// depth-2 counted-vmcnt pipeline runs CONTINUOUSLY across tile boundaries:
// stage step vs+2 while computing vs, vmcnt(4), one barrier per step. The
// per-tile epilogue (shuffles+atomics, no LDS) overlaps next-tile staging.
__global__ __launch_bounds__(256) void k_score(const char* __restrict__ qi8,
                                               const char* __restrict__ ki8,
                                               u64* __restrict__ rowpack,
                                               u32* __restrict__ colmax) {
    __shared__ char sA[3][128 * 64];
    __shared__ char sB[3][128 * 64];

    int t = threadIdx.x;
    int lane = t & 63;
    int wid = t >> 6;
    int wrow = wid >> 1;
    int wcol = wid & 1;
    int lr = lane & 15;          // frag row (A) / col (B)
    int kc = lane >> 4;          // k-chunk 0..3 (16 i8 each)

    int srow = t >> 2;           // staging row 0..63
    int scolB = (t & 3) * 16;    // staging byte offset in 64B row

    int bid = blockIdx.x;                     // 0..767
    int nt = (2048 - bid + PBLK - 1) / PBLK;  // 2 or 3 tiles
    int total = nt * 8;                       // total K-steps for this block

#define TILE_PTRS(tile, pA, pB)  do {                                  \
        int n0_ = ((tile) >> 4) * 128;                                 \
        int j0_ = ((tile) & 15) * 128;                                 \
        pA = qi8 + (size_t)(n0_ + srow) * DDIM + scolB;                \
        pB = ki8 + (size_t)(j0_ + srow) * DDIM + scolB;                \
    } while (0)

#define STAGE4(buf, pA, pB, koff)  do {                                \
        gld_lds16((pA) + (koff),              &sA[buf][t * 16]);       \
        gld_lds16((pA) + 64 * DDIM + (koff),  &sA[buf][4096 + t * 16]);\
        gld_lds16((pB) + (koff),              &sB[buf][t * 16]);       \
        gld_lds16((pB) + 64 * DDIM + (koff),  &sB[buf][4096 + t * 16]);\
    } while (0)

    i32x4 acc[4][4] = {};

    // prologue: stage steps 0,1 of first tile
    {
        const char *pA, *pB;
        TILE_PTRS(bid, pA, pB);
        STAGE4(0, pA, pB, 0);
        STAGE4(1, pA, pB, 64);
    }
    asm volatile("s_waitcnt vmcnt(4)" ::: "memory");
    __builtin_amdgcn_s_barrier();
    __builtin_amdgcn_sched_barrier(0);

    int b0 = 0;   // buffer index of step 0 of current tile
    #pragma unroll 1
    for (int tt = 0; tt < nt; ++tt) {
        int tileC = bid + tt * PBLK;
        int n0 = (tileC >> 4) * 128;
        int j0 = (tileC & 15) * 128;
        int tileN = (tt + 1 < nt) ? tileC + PBLK : tileC;   // clamped (unused if last)
        const char *cA, *cB, *nA, *nB;
        TILE_PTRS(tileC, cA, cB);
        TILE_PTRS(tileN, nA, nB);
        int bufs[3] = { b0, (b0 + 1) % 3, (b0 + 2) % 3 };   // compile-time indexed

        #pragma unroll
        for (int kt = 0; kt < 8; ++kt) {
            int vs = tt * 8 + kt;
            // 1. stage step vs+2 (same tile: k-offset; kt>=6: next tile steps 0,1)
            if (vs + 2 < total) {
                int sbuf = bufs[(kt + 2) % 3];
                if (kt < 6) STAGE4(sbuf, cA, cB, (kt + 2) * 64);
                else        STAGE4(sbuf, nA, nB, (kt - 6) * 64);
            }
            // 2. compute step vs from bufs[kt%3]
            {
                int cbuf = bufs[kt % 3];
                i32x4 a[4], b[4];
                #pragma unroll
                for (int i = 0; i < 4; ++i)
                    a[i] = *(const i32x4*)&sA[cbuf][(wrow * 64 + i * 16 + lr) * 64 + kc * 16];
                #pragma unroll
                for (int j = 0; j < 4; ++j)
                    b[j] = *(const i32x4*)&sB[cbuf][(wcol * 64 + j * 16 + lr) * 64 + kc * 16];
                #pragma unroll
                for (int i = 0; i < 4; ++i)
                    #pragma unroll
                    for (int j = 0; j < 4; ++j)
                        acc[i][j] = __builtin_amdgcn_mfma_i32_16x16x64_i8(a[i], b[j], acc[i][j], 0, 0, 0);
            }
            // 3. gate next buffer (never drain mid-pipeline)
            if (vs + 2 < total)       asm volatile("s_waitcnt vmcnt(4)" ::: "memory");
            else if (vs == total - 2) asm volatile("s_waitcnt vmcnt(0)" ::: "memory");
            // 4. barrier (not after the very last step)
            if (vs < total - 1) {
                __builtin_amdgcn_s_barrier();
                __builtin_amdgcn_sched_barrier(0);
            }
        }

        // ---- per-tile epilogue (int scores; no LDS -> overlaps in-flight staging) ----
        // C/D layout: col = lane&15 (=lr), row = (lane>>4)*4 + reg (=kc*4+r)
        #pragma unroll
        for (int i = 0; i < 4; ++i) {
            #pragma unroll
            for (int r = 0; r < 4; ++r) {
                int v = acc[i][0][r];
                int c = j0 + wcol * 64 + lr;
                #pragma unroll
                for (int j = 1; j < 4; ++j) {
                    int vj = acc[i][j][r];
                    int cj = j0 + wcol * 64 + j * 16 + lr;
                    if (vj > v) { v = vj; c = cj; }
                }
                #pragma unroll
                for (int off = 1; off < 16; off <<= 1) {
                    int ov = __shfl_xor(v, off, 64);
                    int oc = __shfl_xor(c, off, 64);
                    if (ov > v || (ov == v && oc < c)) { v = ov; c = oc; }
                }
                if (lr == 0) {
                    int grow = n0 + wrow * 64 + i * 16 + kc * 4 + r;
                    u64 pk = ((u64)(u32)(v ^ 0x80000000) << 32) | (u64)(~(u32)c);
                    atomicMax(rowpack + grow, pk);
                }
            }
        }
        #pragma unroll
        for (int j = 0; j < 4; ++j) {
            int m = acc[0][j][0];
            #pragma unroll
            for (int i = 0; i < 4; ++i)
                #pragma unroll
                for (int r = 0; r < 4; ++r) m = max(m, acc[i][j][r]);
            m = max(m, __shfl_xor(m, 16, 64));
            m = max(m, __shfl_xor(m, 32, 64));
            if (kc == 0) atomicMax(colmax + j0 + wcol * 64 + j * 16 + lr,
                                   (u32)m ^ 0x80000000u);   // biased: zero-init == -inf
        }
        // reset accumulators for next tile
        #pragma unroll
        for (int i = 0; i < 4; ++i)
            #pragma unroll
            for (int j = 0; j < 4; ++j)
                acc[i][j] = (i32x4){0, 0, 0, 0};

        b0 = (b0 + 2) % 3;   // (b0 + 8) % 3
    }
#undef STAGE4
#undef TILE_PTRS
}

// ---------- kernel 3: bucket-claim fill ----------
__global__ __launch_bounds__(256) void k_fill(const u64* __restrict__ rowpack,
                                              const u32* __restrict__ colmax,
                                              u32* __restrict__ cur,
                                              u32* __restrict__ bperm,
                                              float* __restrict__ bw,
                                              u32* __restrict__ ovf_cnt,
                                              u32* __restrict__ ovf_n,
                                              float* __restrict__ ovf_w) {
    int n = blockIdx.x * 256 + threadIdx.x;
    u64 p = rowpack[n];
    int vi = (int)(((u32)(p >> 32)) ^ 0x80000000u);
    int g = (int)(~(u32)(p & 0xFFFFFFFFull));
    int cm = (int)(colmax[g] ^ 0x80000000u);
    float w = expf((float)(vi - cm) * INV_S);   // <= 1
    u32 pos = atomicAdd(cur + g, 1u);
    if (pos < BCAP) {
        bperm[g * BCAP + pos] = (u32)n;
        bw[g * BCAP + pos] = w;
    } else {
        u32 o = atomicAdd(ovf_cnt, 1u);
        ovf_n[o] = ((u32)g << 16) | (u32)n;
        ovf_w[o] = w;
    }
}

// ---------- kernel 4: gather + final normalize (fused) ----------
__global__ __launch_bounds__(128) void k_gather_final(const char* __restrict__ qi8,
                                                      const u32* __restrict__ cur,
                                                      const u32* __restrict__ bperm,
                                                      const float* __restrict__ bw,
                                                      const u32* __restrict__ ovf_cnt,
                                                      const u32* __restrict__ ovf_n,
                                                      const float* __restrict__ ovf_w,
                                                      const float* __restrict__ keys,
                                                      float* __restrict__ out) {
    __shared__ float sred[2];
    int j = blockIdx.x;
    int t = threadIdx.x;
    u32 c = cur[j];
    u32 cnt = c < BCAP ? c : BCAP;
    float ax = 0.f, ay = 0.f, az = 0.f, aw = 0.f;
    for (u32 i = 0; i < cnt; ++i) {
        u32 n = bperm[j * BCAP + i];
        float wq = bw[j * BCAP + i] * (1.0f / 127.0f);
        char4 q4 = ((const char4*)(qi8 + (size_t)n * DDIM))[t];
        ax = fmaf(wq, (float)q4.x, ax);
        ay = fmaf(wq, (float)q4.y, ay);
        az = fmaf(wq, (float)q4.z, az);
        aw = fmaf(wq, (float)q4.w, aw);
    }
    if (c > BCAP) {                      // rare overflow path (wave-uniform)
        u32 oc = *ovf_cnt;
        for (u32 i = 0; i < oc; ++i) {
            u32 e = ovf_n[i];
            if ((e >> 16) == (u32)j) {
                u32 n = e & 0xFFFFu;
                float wq = ovf_w[i] * (1.0f / 127.0f);
                char4 q4 = ((const char4*)(qi8 + (size_t)n * DDIM))[t];
                ax = fmaf(wq, (float)q4.x, ax);
                ay = fmaf(wq, (float)q4.y, ay);
                az = fmaf(wq, (float)q4.z, az);
                aw = fmaf(wq, (float)q4.w, aw);
            }
        }
    }
    float4 k4 = ((const float4*)(keys + (size_t)j * DDIM))[t];
    float4 v;
    v.x = fmaf(TEMPU, ax, k4.x);
    v.y = fmaf(TEMPU, ay, k4.y);
    v.z = fmaf(TEMPU, az, k4.z);
    v.w = fmaf(TEMPU, aw, k4.w);
    float ss = v.x * v.x + v.y * v.y + v.z * v.z + v.w * v.w;
    ss = block_reduce_sum_128(ss, sred, t);
    float inv = 1.0f / fmaxf(sqrtf(ss), EPSN);
    v.x *= inv; v.y *= inv; v.z *= inv; v.w *= inv;
    ((float4*)(out + (size_t)j * DDIM))[t] = v;
}

// ---------- launch ----------
extern "C" void kernel_launch(void* const* d_in, const int* in_sizes, int n_in,
                              void* d_out, int out_size, void* d_ws, size_t ws_size,
                              hipStream_t stream) {
    const float* query = (const float*)d_in[0];   // [16384, 512] f32
    const float* keys  = (const float*)d_in[1];   // [2048, 512] f32
    float* out = (float*)d_out;                   // [2048, 512] f32

    char* ws = (char*)d_ws;
    const size_t OFF_QI8   = 0;                        //  8,388,608 B
    const size_t OFF_ROW   = 8388608;                  //    131,072 B  rowpack u64[16384]
    const size_t OFF_CMAX  = OFF_ROW + 131072;         //      8,192 B  colmax u32 biased
    const size_t OFF_CUR   = OFF_CMAX + 8192;          //      8,192 B  cur u32[2048]
    const size_t OFF_OVFC  = OFF_CUR + 8192;           //      2,048 B  ovf_cnt (padded)
    const size_t OFF_BPERM = OFF_OVFC + 2048;          //    262,144 B  bperm u32[2048][32]
    const size_t OFF_BW    = OFF_BPERM + 262144;       //    262,144 B  bw f32[2048][32]
    const size_t OFF_OVFN  = OFF_BW + 262144;          //     65,536 B  ovf_n
    const size_t OFF_OVFW  = OFF_OVFN + 65536;         //     65,536 B  ovf_w
    const size_t OFF_KI8   = OFF_OVFW + 65536;         //  1,048,576 B

    char*   qi8    = ws + OFF_QI8;
    u64*    rowpack= (u64*)(ws + OFF_ROW);
    u32*    cmax   = (u32*)(ws + OFF_CMAX);
    u32*    cur    = (u32*)(ws + OFF_CUR);
    u32*    ovfc   = (u32*)(ws + OFF_OVFC);
    u32*    bperm  = (u32*)(ws + OFF_BPERM);
    float*  bw     = (float*)(ws + OFF_BW);
    u32*    ovfn   = (u32*)(ws + OFF_OVFN);
    float*  ovfw   = (float*)(ws + OFF_OVFW);
    char*   ki8    = ws + OFF_KI8;

    // k_prep zero-fills rowpack+colmax+cur+ovf_cnt (last NZBLK blocks)
    k_prep<<<N_Q + M_SLOTS + NZBLK, 128, 0, stream>>>(query, keys, qi8, ki8,
                                                      (float4*)(ws + OFF_ROW));

    k_score<<<PBLK, 256, 0, stream>>>(qi8, ki8, rowpack, cmax);

    k_fill<<<N_Q / 256, 256, 0, stream>>>(rowpack, cmax, cur, bperm, bw,
                                          ovfc, ovfn, ovfw);
    k_gather_final<<<M_SLOTS, 128, 0, stream>>>(qi8, cur, bperm, bw,
                                                ovfc, ovfn, ovfw, keys, out);
}

// Round 14
// 78.143 us; speedup vs baseline: 1.1443x; 1.1443x over previous
//
#include <hip/hip_runtime.h>
#include <math.h>

#define N_Q     16384
#define DDIM    512
#define M_SLOTS 2048
#define EPSN    1e-12f
#define TEMPU   1e-5f
#define KSCALE  25.4f                    // int8 scale for keys (clips at ~5 sigma)
#define QSCALE  127.0f
#define INV_S   (1.0f / (127.0f * 25.4f))
#define NZBLK   73                       // zero-fill blocks appended to k_prep (73*2048B)
#define BCAP    32                       // bucket capacity per slot (Poisson(8): P(>32)~1e-9)

typedef unsigned int u32;
typedef unsigned long long u64;
typedef __attribute__((ext_vector_type(4))) int i32x4;

// ---------- helpers ----------
__device__ __forceinline__ void gld_lds16(const void* g, void* l) {
    __builtin_amdgcn_global_load_lds(
        (const __attribute__((address_space(1))) u32*)(g),
        (__attribute__((address_space(3))) u32*)(l), 16, 0, 0);
}
__device__ __forceinline__ float block_reduce_sum_128(float v, float* sred, int t) {
    #pragma unroll
    for (int o = 32; o > 0; o >>= 1) v += __shfl_down(v, o, 64);
    if ((t & 63) == 0) sred[t >> 6] = v;
    __syncthreads();
    return sred[0] + sred[1];
}
__device__ __forceinline__ char q8(float x, float s) {
    int v = __float2int_rn(x * s);
    v = v < -127 ? -127 : (v > 127 ? 127 : v);
    return (char)v;
}

// ---------- kernel 1: normalize+quantize queries / keys->i8 / zero-fill scratch ----------
__global__ __launch_bounds__(128) void k_prep(const float* __restrict__ q,
                                              const float* __restrict__ keys,
                                              char* __restrict__ qi8,
                                              char* __restrict__ ki8,
                                              float4* __restrict__ zbase) {
    __shared__ float sred[2];
    int b = blockIdx.x;
    int t = threadIdx.x;
    if (b < N_Q) {
        float4 v = ((const float4*)(q + (size_t)b * DDIM))[t];
        float ss = v.x * v.x + v.y * v.y + v.z * v.z + v.w * v.w;
        ss = block_reduce_sum_128(ss, sred, t);
        float s = QSCALE / fmaxf(sqrtf(ss), EPSN);
        char4 o;
        o.x = q8(v.x, s);
        o.y = q8(v.y, s);
        o.z = q8(v.z, s);
        o.w = q8(v.w, s);
        ((char4*)(qi8 + (size_t)b * DDIM))[t] = o;
    } else if (b < N_Q + M_SLOTS) {
        int r = b - N_Q;
        float4 v = ((const float4*)(keys + (size_t)r * DDIM))[t];
        char4 o;
        o.x = q8(v.x, KSCALE);
        o.y = q8(v.y, KSCALE);
        o.z = q8(v.z, KSCALE);
        o.w = q8(v.w, KSCALE);
        ((char4*)(ki8 + (size_t)r * DDIM))[t] = o;
    } else {
        // zero rowpack(131072) + colmax(8192) + cur(8192) + ovf_cnt pad(2048)
        int idx = (b - (N_Q + M_SLOTS)) * 128 + t;
        zbase[idx] = make_float4(0.f, 0.f, 0.f, 0.f);
    }
}

// ---------- kernel 2: i8 MFMA score GEMM — barrier-free, A-in-registers ----------
// Tile 128x64, 4 waves x 32 rows. B (64 slots x K=512 = 32 KB) staged ONCE,
// swizzled (r8's measured-conflict-free pattern). A (32 rows x 512 per wave)
// loaded ONCE into 64 VGPR/lane and pinned via asm uses (r9's failure mode was
// the compiler sinking these loads; the pin forces materialization). K-loop is
// pure ds_read->MFMA: no barriers, no global access; waves free-run.
__global__ __launch_bounds__(256) void k_score(const char* __restrict__ qi8,
                                               const char* __restrict__ ki8,
                                               u64* __restrict__ rowpack,
                                               u32* __restrict__ colmax) {
    __shared__ char sB[64 * 512];   // 32 KB

    int t = threadIdx.x;
    int lane = t & 63;
    int w = t >> 6;              // wave 0..3 -> rows w*32..+32
    int lr = lane & 15;          // frag row (A) / col (B)
    int kc = lane >> 4;          // k-chunk 0..3 (16 i8 each)

    int j0 = blockIdx.x * 64;    // slot block (64 cols)
    int n0 = blockIdx.y * 128;   // query block (128 rows)
    int wr0 = n0 + w * 32;       // this wave's first row

    // ---- stage B once, swizzled: 2048 16B-chunks, 8 per thread ----
    // chunk m: row=m>>5, slot=m&31; source col = (slot*16)^((row&15)<<4).
    // gld_lds dest is linear (wave-uniform base + lane*16) per G21.
    #pragma unroll
    for (int i = 0; i < 8; ++i) {
        int m = i * 256 + t;
        int row = m >> 5;
        int slot = m & 31;
        int gcol = (slot * 16) ^ ((row & 15) << 4);
        gld_lds16(ki8 + (size_t)(j0 + row) * DDIM + gcol, &sB[m * 16]);
    }

    // ---- A into registers, pinned ----
    const char* ga0 = qi8 + (size_t)(wr0 + lr) * DDIM + kc * 16;
    const char* ga1 = qi8 + (size_t)(wr0 + 16 + lr) * DDIM + kc * 16;
    i32x4 a[8][2];
    #pragma unroll
    for (int kt = 0; kt < 8; ++kt) {
        a[kt][0] = *(const i32x4*)(ga0 + kt * 64);
        a[kt][1] = *(const i32x4*)(ga1 + kt * 64);
    }
    #pragma unroll
    for (int kt = 0; kt < 8; ++kt)
        asm volatile("" :: "v"(a[kt][0]), "v"(a[kt][1]));   // force resident (rule #17)

    asm volatile("s_waitcnt vmcnt(0)" ::: "memory");
    __syncthreads();             // the only barrier: B staged

    // ---- barrier-free K-loop ----
    i32x4 acc[2][4] = {};
    #pragma unroll
    for (int kt = 0; kt < 8; ++kt) {
        i32x4 b[4];
        #pragma unroll
        for (int jj = 0; jj < 4; ++jj)
            b[jj] = *(const i32x4*)&sB[(jj * 16 + lr) * 512 +
                                       ((kt * 64 + kc * 16) ^ (lr << 4))];
        #pragma unroll
        for (int i = 0; i < 2; ++i)
            #pragma unroll
            for (int jj = 0; jj < 4; ++jj)
                acc[i][jj] = __builtin_amdgcn_mfma_i32_16x16x64_i8(a[kt][i], b[jj], acc[i][jj], 0, 0, 0);
    }

    // ---- fused epilogue (int scores) ----
    // C/D layout: col = lane&15 (=lr), row = (lane>>4)*4 + reg (=kc*4+r)
    #pragma unroll
    for (int i = 0; i < 2; ++i) {
        #pragma unroll
        for (int r = 0; r < 4; ++r) {
            int v = acc[i][0][r];
            int c = j0 + lr;
            #pragma unroll
            for (int jj = 1; jj < 4; ++jj) {
                int vj = acc[i][jj][r];
                int cj = j0 + jj * 16 + lr;
                if (vj > v) { v = vj; c = cj; }
            }
            #pragma unroll
            for (int off = 1; off < 16; off <<= 1) {
                int ov = __shfl_xor(v, off, 64);
                int oc = __shfl_xor(c, off, 64);
                if (ov > v || (ov == v && oc < c)) { v = ov; c = oc; }
            }
            if (lr == 0) {
                int grow = wr0 + i * 16 + kc * 4 + r;
                u64 pk = ((u64)(u32)(v ^ 0x80000000) << 32) | (u64)(~(u32)c);
                atomicMax(rowpack + grow, pk);
            }
        }
    }
    #pragma unroll
    for (int jj = 0; jj < 4; ++jj) {
        int m = acc[0][jj][0];
        #pragma unroll
        for (int i = 0; i < 2; ++i)
            #pragma unroll
            for (int r = 0; r < 4; ++r) m = max(m, acc[i][jj][r]);
        m = max(m, __shfl_xor(m, 16, 64));
        m = max(m, __shfl_xor(m, 32, 64));
        if (kc == 0) atomicMax(colmax + j0 + jj * 16 + lr,
                               (u32)m ^ 0x80000000u);   // biased: zero-init == -inf
    }
}

// ---------- kernel 3: bucket-claim fill ----------
__global__ __launch_bounds__(256) void k_fill(const u64* __restrict__ rowpack,
                                              const u32* __restrict__ colmax,
                                              u32* __restrict__ cur,
                                              u32* __restrict__ bperm,
                                              float* __restrict__ bw,
                                              u32* __restrict__ ovf_cnt,
                                              u32* __restrict__ ovf_n,
                                              float* __restrict__ ovf_w) {
    int n = blockIdx.x * 256 + threadIdx.x;
    u64 p = rowpack[n];
    int vi = (int)(((u32)(p >> 32)) ^ 0x80000000u);
    int g = (int)(~(u32)(p & 0xFFFFFFFFull));
    int cm = (int)(colmax[g] ^ 0x80000000u);
    float w = expf((float)(vi - cm) * INV_S);   // <= 1
    u32 pos = atomicAdd(cur + g, 1u);
    if (pos < BCAP) {
        bperm[g * BCAP + pos] = (u32)n;
        bw[g * BCAP + pos] = w;
    } else {
        u32 o = atomicAdd(ovf_cnt, 1u);
        ovf_n[o] = ((u32)g << 16) | (u32)n;
        ovf_w[o] = w;
    }
}

// ---------- kernel 4: gather + final normalize (fused) ----------
__global__ __launch_bounds__(128) void k_gather_final(const char* __restrict__ qi8,
                                                      const u32* __restrict__ cur,
                                                      const u32* __restrict__ bperm,
                                                      const float* __restrict__ bw,
                                                      const u32* __restrict__ ovf_cnt,
                                                      const u32* __restrict__ ovf_n,
                                                      const float* __restrict__ ovf_w,
                                                      const float* __restrict__ keys,
                                                      float* __restrict__ out) {
    __shared__ float sred[2];
    int j = blockIdx.x;
    int t = threadIdx.x;
    u32 c = cur[j];
    u32 cnt = c < BCAP ? c : BCAP;
    float ax = 0.f, ay = 0.f, az = 0.f, aw = 0.f;
    for (u32 i = 0; i < cnt; ++i) {
        u32 n = bperm[j * BCAP + i];
        float wq = bw[j * BCAP + i] * (1.0f / 127.0f);
        char4 q4 = ((const char4*)(qi8 + (size_t)n * DDIM))[t];
        ax = fmaf(wq, (float)q4.x, ax);
        ay = fmaf(wq, (float)q4.y, ay);
        az = fmaf(wq, (float)q4.z, az);
        aw = fmaf(wq, (float)q4.w, aw);
    }
    if (c > BCAP) {                      // rare overflow path (wave-uniform)
        u32 oc = *ovf_cnt;
        for (u32 i = 0; i < oc; ++i) {
            u32 e = ovf_n[i];
            if ((e >> 16) == (u32)j) {
                u32 n = e & 0xFFFFu;
                float wq = ovf_w[i] * (1.0f / 127.0f);
                char4 q4 = ((const char4*)(qi8 + (size_t)n * DDIM))[t];
                ax = fmaf(wq, (float)q4.x, ax);
                ay = fmaf(wq, (float)q4.y, ay);
                az = fmaf(wq, (float)q4.z, az);
                aw = fmaf(wq, (float)q4.w, aw);
            }
        }
    }
    float4 k4 = ((const float4*)(keys + (size_t)j * DDIM))[t];
    float4 v;
    v.x = fmaf(TEMPU, ax, k4.x);
    v.y = fmaf(TEMPU, ay, k4.y);
    v.z = fmaf(TEMPU, az, k4.z);
    v.w = fmaf(TEMPU, aw, k4.w);
    float ss = v.x * v.x + v.y * v.y + v.z * v.z + v.w * v.w;
    ss = block_reduce_sum_128(ss, sred, t);
    float inv = 1.0f / fmaxf(sqrtf(ss), EPSN);
    v.x *= inv; v.y *= inv; v.z *= inv; v.w *= inv;
    ((float4*)(out + (size_t)j * DDIM))[t] = v;
}

// ---------- launch ----------
extern "C" void kernel_launch(void* const* d_in, const int* in_sizes, int n_in,
                              void* d_out, int out_size, void* d_ws, size_t ws_size,
                              hipStream_t stream) {
    const float* query = (const float*)d_in[0];   // [16384, 512] f32
    const float* keys  = (const float*)d_in[1];   // [2048, 512] f32
    float* out = (float*)d_out;                   // [2048, 512] f32

    char* ws = (char*)d_ws;
    const size_t OFF_QI8   = 0;                        //  8,388,608 B
    const size_t OFF_ROW   = 8388608;                  //    131,072 B  rowpack u64[16384]
    const size_t OFF_CMAX  = OFF_ROW + 131072;         //      8,192 B  colmax u32 biased
    const size_t OFF_CUR   = OFF_CMAX + 8192;          //      8,192 B  cur u32[2048]
    const size_t OFF_OVFC  = OFF_CUR + 8192;           //      2,048 B  ovf_cnt (padded)
    const size_t OFF_BPERM = OFF_OVFC + 2048;          //    262,144 B  bperm u32[2048][32]
    const size_t OFF_BW    = OFF_BPERM + 262144;       //    262,144 B  bw f32[2048][32]
    const size_t OFF_OVFN  = OFF_BW + 262144;          //     65,536 B  ovf_n
    const size_t OFF_OVFW  = OFF_OVFN + 65536;         //     65,536 B  ovf_w
    const size_t OFF_KI8   = OFF_OVFW + 65536;         //  1,048,576 B

    char*   qi8    = ws + OFF_QI8;
    u64*    rowpack= (u64*)(ws + OFF_ROW);
    u32*    cmax   = (u32*)(ws + OFF_CMAX);
    u32*    cur    = (u32*)(ws + OFF_CUR);
    u32*    ovfc   = (u32*)(ws + OFF_OVFC);
    u32*    bperm  = (u32*)(ws + OFF_BPERM);
    float*  bw     = (float*)(ws + OFF_BW);
    u32*    ovfn   = (u32*)(ws + OFF_OVFN);
    float*  ovfw   = (float*)(ws + OFF_OVFW);
    char*   ki8    = ws + OFF_KI8;

    // k_prep zero-fills rowpack+colmax+cur+ovf_cnt (last NZBLK blocks)
    k_prep<<<N_Q + M_SLOTS + NZBLK, 128, 0, stream>>>(query, keys, qi8, ki8,
                                                      (float4*)(ws + OFF_ROW));

    dim3 g2(M_SLOTS / 64, N_Q / 128);  // 32 x 128
    k_score<<<g2, 256, 0, stream>>>(qi8, ki8, rowpack, cmax);

    k_fill<<<N_Q / 256, 256, 0, stream>>>(rowpack, cmax, cur, bperm, bw,
                                          ovfc, ovfn, ovfw);
    k_gather_final<<<M_SLOTS, 128, 0, stream>>>(qi8, cur, bperm, bw,
                                                ovfc, ovfn, ovfw, keys, out);
}